// Round 1
// baseline (142.452 us; speedup 1.0000x reference)
//
#include <hip/hip_runtime.h>

using f32x4 = __attribute__((ext_vector_type(4))) float;
using h16x4 = __attribute__((ext_vector_type(4))) _Float16;
using h16x8 = __attribute__((ext_vector_type(8))) _Float16;

#define NEGBIG (-1e30f)

// B=4, H=8, N=2048, E=64. fp32 in/out; f16 MFMA internally.
// Grid: (N/64 q-blocks, B*H). Block: 256 threads = 4 waves, 16 q-rows/wave.
__launch_bounds__(256)
__global__ void attn_kernel(const float* __restrict__ Qg,
                            const float* __restrict__ Kg,
                            const float* __restrict__ Vg,
                            const int*   __restrict__ seqlens,
                            float*       __restrict__ Og)
{
    constexpr int N = 2048, E = 64;
    const int qblk = blockIdx.x;
    const int bh   = blockIdx.y;
    const int b    = bh >> 3;          // H = 8
    const int seqlen = seqlens[b];
    const int qstart = qblk * 64;
    const int tid = threadIdx.x;

    float* Ob = Og + ((size_t)bh * N + qstart) * E;

    // Whole q-block beyond seqlen: output is zero. (d_out is poisoned.)
    if (qstart >= seqlen) {
        f32x4 z = {0.f, 0.f, 0.f, 0.f};
        f32x4* op = (f32x4*)Ob;
        #pragma unroll
        for (int i = 0; i < 4; ++i) op[tid + i * 256] = z;
        return;
    }

    const float* Qb = Qg + (size_t)bh * N * E;
    const float* Kb = Kg + (size_t)bh * N * E;
    const float* Vb = Vg + (size_t)bh * N * E;

    // K tile: [64 keys][64 e] f16, 16B-chunk XOR swizzle (chunk ^ (row&7)).
    // V tile: transposed [64 e][64 keys] f16, 8B-chunk XOR swizzle (c8 ^ ((e&7)<<1)).
    __shared__ __attribute__((aligned(16))) _Float16 Ksh[64 * 64];
    __shared__ __attribute__((aligned(16))) _Float16 Vsh[64 * 64];

    const int wid  = tid >> 6;
    const int lane = tid & 63;
    const int lg   = lane >> 4;   // 0..3 (16-lane group)
    const int l16  = lane & 15;

    // Q fragments (B operand of 16x16x32): Qf[es][j] = Q[qrow][es*32 + lg*8 + j]
    const int qrow = qstart + wid * 16 + l16;
    h16x8 Qf[2];
    #pragma unroll
    for (int es = 0; es < 2; ++es) {
        const f32x4* qp = (const f32x4*)(Qb + (size_t)qrow * E + es * 32 + lg * 8);
        f32x4 x = qp[0], y = qp[1];
        h16x8 h;
        h[0]=(_Float16)x[0]; h[1]=(_Float16)x[1]; h[2]=(_Float16)x[2]; h[3]=(_Float16)x[3];
        h[4]=(_Float16)y[0]; h[5]=(_Float16)y[1]; h[6]=(_Float16)y[2]; h[7]=(_Float16)y[3];
        Qf[es] = h;
    }

    float m = NEGBIG, L = 0.f;
    f32x4 Ot[4] = {{0,0,0,0},{0,0,0,0},{0,0,0,0},{0,0,0,0}};

    const int vkey    = tid & 63;
    const int ve0base = (tid >> 6) * 8;

    for (int kstart = 0; kstart < seqlen; kstart += 64) {
        __syncthreads();   // previous tile's LDS reads complete before overwrite

        // ---- stage K tile (row-major, swizzled) ----
        #pragma unroll
        for (int it = 0; it < 2; ++it) {
            int cid = tid + it * 256;          // 512 chunks of 8 f16
            int r = cid >> 3, c = cid & 7;
            const f32x4* gp = (const f32x4*)(Kb + (size_t)(kstart + r) * E + c * 8);
            f32x4 x = gp[0], y = gp[1];
            h16x8 h;
            h[0]=(_Float16)x[0]; h[1]=(_Float16)x[1]; h[2]=(_Float16)x[2]; h[3]=(_Float16)x[3];
            h[4]=(_Float16)y[0]; h[5]=(_Float16)y[1]; h[6]=(_Float16)y[2]; h[7]=(_Float16)y[3];
            *(h16x8*)&Ksh[r * 64 + ((c ^ (r & 7)) << 3)] = h;
        }
        // ---- stage V^T tile (transposed, swizzled) ----
        #pragma unroll
        for (int p = 0; p < 2; ++p) {
            int e0 = ve0base + p * 32;
            const f32x4* gp = (const f32x4*)(Vb + (size_t)(kstart + vkey) * E + e0);
            f32x4 x = gp[0], y = gp[1];
            float vv[8] = {x[0], x[1], x[2], x[3], y[0], y[1], y[2], y[3]};
            #pragma unroll
            for (int i = 0; i < 8; ++i) {
                int e = e0 + i;
                Vsh[e * 64 + (((vkey >> 2) ^ ((e & 7) << 1)) << 2) + (vkey & 3)] =
                    (_Float16)vv[i];
            }
        }
        __syncthreads();

        // ---- S^T = K · Q^T : St[kt] row=key(4*lg+j), col=q(l16) ----
        f32x4 St[4];
        #pragma unroll
        for (int kt = 0; kt < 4; ++kt) {
            f32x4 acc = {0, 0, 0, 0};
            int key = kt * 16 + l16;
            #pragma unroll
            for (int es = 0; es < 2; ++es) {
                int c = es * 4 + lg;
                h16x8 kf = *(const h16x8*)&Ksh[key * 64 + ((c ^ (key & 7)) << 3)];
                acc = __builtin_amdgcn_mfma_f32_16x16x32_f16(kf, Qf[es], acc, 0, 0, 0);
            }
            St[kt] = acc;
        }
        // mask keys >= seqlen (tail tile only; wave-uniform branch)
        if (kstart + 64 > seqlen) {
            #pragma unroll
            for (int kt = 0; kt < 4; ++kt) {
                int kbase = kstart + kt * 16 + lg * 4;
                #pragma unroll
                for (int j = 0; j < 4; ++j)
                    if (kbase + j >= seqlen) St[kt][j] = NEGBIG;
            }
        }

        // ---- online softmax (per-lane q-row; reduce across 4 key-groups) ----
        float tm = NEGBIG;
        #pragma unroll
        for (int kt = 0; kt < 4; ++kt)
            #pragma unroll
            for (int j = 0; j < 4; ++j) tm = fmaxf(tm, St[kt][j]);
        tm = fmaxf(tm, __shfl_xor(tm, 16));
        tm = fmaxf(tm, __shfl_xor(tm, 32));

        float mn = fmaxf(m, tm);
        float scale = __expf(m - mn);
        m = mn;

        float ps = 0.f;
        h16x4 Pf[4];
        #pragma unroll
        for (int kt = 0; kt < 4; ++kt) {
            #pragma unroll
            for (int j = 0; j < 4; ++j) {
                float pv = __expf(St[kt][j] - mn);   // masked -> exactly 0
                ps += pv;
                Pf[kt][j] = (_Float16)pv;
            }
        }
        ps += __shfl_xor(ps, 16);
        ps += __shfl_xor(ps, 32);
        L = L * scale + ps;

        #pragma unroll
        for (int et = 0; et < 4; ++et) Ot[et] *= scale;

        // ---- O^T += V^T · P^T (16x16x16 f16; P^T layout == St layout) ----
        #pragma unroll
        for (int kt = 0; kt < 4; ++kt) {
            #pragma unroll
            for (int et = 0; et < 4; ++et) {
                int e  = et * 16 + l16;
                int c8 = kt * 4 + lg;
                h16x4 vf = *(const h16x4*)&Vsh[e * 64 + ((c8 ^ ((e & 7) << 1)) << 2)];
                Ot[et] = __builtin_amdgcn_mfma_f32_16x16x16f16(vf, Pf[kt], Ot[et], 0, 0, 0);
            }
        }
    }

    // ---- epilogue: Ot[et][j] = O^T[e = et*16 + lg*4 + j][q = l16] ----
    float invL = 1.f / L;
    float* orow = Ob + (size_t)(wid * 16 + l16) * E;
    if (qrow < seqlen) {
        #pragma unroll
        for (int et = 0; et < 4; ++et) {
            f32x4 o = Ot[et] * invL;
            *(f32x4*)(orow + et * 16 + lg * 4) = o;
        }
    } else {
        f32x4 z = {0, 0, 0, 0};
        #pragma unroll
        for (int et = 0; et < 4; ++et)
            *(f32x4*)(orow + et * 16 + lg * 4) = z;
    }
}

extern "C" void kernel_launch(void* const* d_in, const int* in_sizes, int n_in,
                              void* d_out, int out_size, void* d_ws, size_t ws_size,
                              hipStream_t stream)
{
    const float* Q = (const float*)d_in[0];
    const float* K = (const float*)d_in[1];
    const float* V = (const float*)d_in[2];
    const int*   S = (const int*)d_in[3];
    float*       O = (float*)d_out;

    dim3 grid(2048 / 64, 4 * 8);   // (q-blocks, B*H)
    attn_kernel<<<grid, 256, 0, stream>>>(Q, K, V, S, O);
}

// Round 3
// 131.863 us; speedup vs baseline: 1.0803x; 1.0803x over previous
//
#include <hip/hip_runtime.h>

using f32x4  = __attribute__((ext_vector_type(4))) float;
using h16x2  = __attribute__((ext_vector_type(2))) _Float16;
using h16x4  = __attribute__((ext_vector_type(4))) _Float16;
using h16x8  = __attribute__((ext_vector_type(8))) _Float16;
using fp16x2 = __attribute__((ext_vector_type(2))) __fp16;   // cvt_pkrtz result type

#define NEGBIG (-1e30f)
#define LOG2E  1.44269504f

__device__ inline h16x8 cvt8(f32x4 x, f32x4 y) {
    union { h16x8 v; fp16x2 p[4]; } u;
    u.p[0] = __builtin_amdgcn_cvt_pkrtz(x[0], x[1]);
    u.p[1] = __builtin_amdgcn_cvt_pkrtz(x[2], x[3]);
    u.p[2] = __builtin_amdgcn_cvt_pkrtz(y[0], y[1]);
    u.p[3] = __builtin_amdgcn_cvt_pkrtz(y[2], y[3]);
    return u.v;
}

// B=4, H=8, N=2048, E=64. fp32 in/out; f16 MFMA in log2-scaled score domain.
// Block: 512 thr = 8 waves; two 64-row q-subtiles share one K/V LDS stage.
// Grid: (N/128, B*H).
__launch_bounds__(512)
__global__ void attn_kernel(const float* __restrict__ Qg,
                            const float* __restrict__ Kg,
                            const float* __restrict__ Vg,
                            const int*   __restrict__ seqlens,
                            float*       __restrict__ Og)
{
    constexpr int N = 2048, E = 64;
    const int qblk = blockIdx.x;          // 128-row q block
    const int bh   = blockIdx.y;
    const int b    = bh >> 3;             // H = 8
    const int seqlen = seqlens[b];
    const int qstart = qblk * 128;
    const int tid = threadIdx.x;

    float* Ob = Og + ((size_t)bh * N + qstart) * E;

    if (qstart >= seqlen) {               // whole 128-row block past seqlen
        f32x4 z = {0.f, 0.f, 0.f, 0.f};
        f32x4* op = (f32x4*)Ob;
        #pragma unroll
        for (int i = 0; i < 4; ++i) op[tid + i * 512] = z;
        return;
    }

    const float* Qb = Qg + (size_t)bh * N * E;
    const float* Kb = Kg + (size_t)bh * N * E;
    const float* Vb = Vg + (size_t)bh * N * E;

    // K tile: [64 keys][64 e] f16, 16B-chunk XOR swizzle (chunk ^ (row&7)).
    // V tile: transposed [64 e][64 keys] f16, 8B-chunk XOR swizzle.
    __shared__ __attribute__((aligned(16))) _Float16 Ksh[64 * 64];
    __shared__ __attribute__((aligned(16))) _Float16 Vsh[64 * 64];

    const int wid  = tid >> 6;            // 0..7
    const int qsub = wid >> 2;            // 0/1: which 64-row q-subtile
    const int widq = wid & 3;             // 16-row group within subtile
    const int lane = tid & 63;
    const int lg   = lane >> 4;           // 0..3
    const int l16  = lane & 15;

    const bool active = (qstart + qsub * 64) < seqlen;   // wave-uniform

    // Q fragments (B operand of 16x16x32), pre-scaled by log2(e):
    const int qrow = qstart + qsub * 64 + widq * 16 + l16;
    h16x8 Qf[2];
    #pragma unroll
    for (int es = 0; es < 2; ++es) {
        const f32x4* qp = (const f32x4*)(Qb + (size_t)qrow * E + es * 32 + lg * 8);
        f32x4 x = qp[0] * LOG2E, y = qp[1] * LOG2E;
        Qf[es] = cvt8(x, y);
    }

    // staging assignment (512 threads):
    const int rK  = tid >> 3;             // K row 0..63
    const int cK  = tid & 7;              // K 8-elem chunk
    const int vkey = tid & 63;            // V key
    const int ve0  = (tid >> 6) * 8;      // V e-range start (wave-uniform)

    float m = NEGBIG, L = 0.f;
    f32x4 Ot[4] = {{0,0,0,0},{0,0,0,0},{0,0,0,0},{0,0,0,0}};

    auto loadStage = [&](int ks, f32x4& k0, f32x4& k1, f32x4& v0, f32x4& v1) {
        const f32x4* kp = (const f32x4*)(Kb + (size_t)(ks + rK) * E + cK * 8);
        k0 = kp[0]; k1 = kp[1];
        const f32x4* vp = (const f32x4*)(Vb + (size_t)(ks + vkey) * E + ve0);
        v0 = vp[0]; v1 = vp[1];
    };

    auto writeStage = [&](const f32x4& k0, const f32x4& k1,
                          const f32x4& v0, const f32x4& v1) {
        *(h16x8*)&Ksh[rK * 64 + ((cK ^ (rK & 7)) << 3)] = cvt8(k0, k1);
        float vv[8] = {v0[0], v0[1], v0[2], v0[3], v1[0], v1[1], v1[2], v1[3]};
        #pragma unroll
        for (int i = 0; i < 8; ++i) {     // e&7 == i (ve0 is multiple of 8)
            int e = ve0 + i;
            Vsh[e * 64 + (((vkey >> 2) ^ (i << 1)) << 2) + (vkey & 3)] =
                (_Float16)vv[i];
        }
    };

    auto computeTile = [&](int ks) {
        if (!active) return;              // wave-uniform; no barriers inside
        // ---- S'^T = K · (Q·log2e)^T ----
        f32x4 St[4];
        #pragma unroll
        for (int kt = 0; kt < 4; ++kt) {
            f32x4 acc = {0, 0, 0, 0};
            int key = kt * 16 + l16;
            #pragma unroll
            for (int es = 0; es < 2; ++es) {
                int c = es * 4 + lg;
                h16x8 kf = *(const h16x8*)&Ksh[key * 64 + ((c ^ (key & 7)) << 3)];
                acc = __builtin_amdgcn_mfma_f32_16x16x32_f16(kf, Qf[es], acc, 0, 0, 0);
            }
            St[kt] = acc;
        }
        if (ks + 64 > seqlen) {           // tail-tile key mask
            #pragma unroll
            for (int kt = 0; kt < 4; ++kt) {
                int kb0 = ks + kt * 16 + lg * 4;
                #pragma unroll
                for (int j = 0; j < 4; ++j)
                    if (kb0 + j >= seqlen) St[kt][j] = NEGBIG;
            }
        }
        // ---- online softmax in log2 domain, defer-rescale (THR=8) ----
        float tm = NEGBIG;
        #pragma unroll
        for (int kt = 0; kt < 4; ++kt)
            #pragma unroll
            for (int j = 0; j < 4; ++j) tm = fmaxf(tm, St[kt][j]);
        tm = fmaxf(tm, __shfl_xor(tm, 16));
        tm = fmaxf(tm, __shfl_xor(tm, 32));

        if (__any(tm > m + 8.f)) {
            float mn = fmaxf(m, tm);
            float sc = __builtin_amdgcn_exp2f(m - mn);
            m = mn;
            L *= sc;
            #pragma unroll
            for (int et = 0; et < 4; ++et) Ot[et] *= sc;
        }

        float ps = 0.f;
        h16x4 Pf[4];
        #pragma unroll
        for (int kt = 0; kt < 4; ++kt) {
            float p0 = __builtin_amdgcn_exp2f(St[kt][0] - m);
            float p1 = __builtin_amdgcn_exp2f(St[kt][1] - m);
            float p2 = __builtin_amdgcn_exp2f(St[kt][2] - m);
            float p3 = __builtin_amdgcn_exp2f(St[kt][3] - m);
            ps += (p0 + p1) + (p2 + p3);
            union { h16x4 v; fp16x2 p[2]; } u;
            u.p[0] = __builtin_amdgcn_cvt_pkrtz(p0, p1);
            u.p[1] = __builtin_amdgcn_cvt_pkrtz(p2, p3);
            Pf[kt] = u.v;
        }
        ps += __shfl_xor(ps, 16);
        ps += __shfl_xor(ps, 32);
        L += ps;

        // ---- O^T += V^T · P^T ----
        #pragma unroll
        for (int kt = 0; kt < 4; ++kt) {
            #pragma unroll
            for (int et = 0; et < 4; ++et) {
                int e  = et * 16 + l16;
                int c8 = kt * 4 + lg;
                h16x4 vf = *(const h16x4*)&Vsh[e * 64 + ((c8 ^ ((e & 7) << 1)) << 2)];
                Ot[et] = __builtin_amdgcn_mfma_f32_16x16x16f16(vf, Pf[kt], Ot[et], 0, 0, 0);
            }
        }
    };

    // ---- software-pipelined K loop: load(t+1) in flight under compute(t) ----
    f32x4 kA0, kA1, vA0, vA1, kB0, kB1, vB0, vB1;
    loadStage(0, kA0, kA1, vA0, vA1);
    int ks = 0;
    while (true) {
        __syncthreads();                          // prior tile's LDS reads done
        writeStage(kA0, kA1, vA0, vA1);
        if (ks + 64 < seqlen) loadStage(ks + 64, kB0, kB1, vB0, vB1);
        __syncthreads();
        computeTile(ks);
        ks += 64;
        if (ks >= seqlen) break;

        __syncthreads();
        writeStage(kB0, kB1, vB0, vB1);
        if (ks + 64 < seqlen) loadStage(ks + 64, kA0, kA1, vA0, vA1);
        __syncthreads();
        computeTile(ks);
        ks += 64;
        if (ks >= seqlen) break;
    }

    // ---- epilogue: Ot[et][j] = O^T[e = et*16 + lg*4 + j][q = l16] ----
    float invL = 1.f / L;
    float* orow = Ob + (size_t)(qsub * 64 + widq * 16 + l16) * E;
    if (qrow < seqlen) {
        #pragma unroll
        for (int et = 0; et < 4; ++et) {
            f32x4 o = Ot[et] * invL;
            *(f32x4*)(orow + et * 16 + lg * 4) = o;
        }
    } else {
        f32x4 z = {0, 0, 0, 0};
        #pragma unroll
        for (int et = 0; et < 4; ++et)
            *(f32x4*)(orow + et * 16 + lg * 4) = z;
    }
}

extern "C" void kernel_launch(void* const* d_in, const int* in_sizes, int n_in,
                              void* d_out, int out_size, void* d_ws, size_t ws_size,
                              hipStream_t stream)
{
    const float* Q = (const float*)d_in[0];
    const float* K = (const float*)d_in[1];
    const float* V = (const float*)d_in[2];
    const int*   S = (const int*)d_in[3];
    float*       O = (float*)d_out;

    dim3 grid(2048 / 128, 4 * 8);   // (128-row q-blocks, B*H)
    attn_kernel<<<grid, 512, 0, stream>>>(Q, K, V, S, O);
}